// Round 7
// baseline (492.206 us; speedup 1.0000x reference)
//
#include <hip/hip_runtime.h>

#define N_ROWS 16384
#define N_COLS 4096
#define MARGIN 0.1f
#define BLOCK  256
#define WAVES  4
#define ROWS_PER_WAVE 2
#define NBLK (N_ROWS / (WAVES * ROWS_PER_WAVE))    // 2048 blocks
#define V4_PER_ROW (N_COLS / 4)                    // 1024 vec4 per row

typedef float vf4 __attribute__((ext_vector_type(4)));
typedef int   vi4 __attribute__((ext_vector_type(4)));

// R2 skeleton (full row per wave, all loads up-front, sync-free) with the
// per-row serial chains removed:
//  - one-hot extract is integer: sv |= bits(c) & (-t)  (t in {0,1}, so -t is
//    an all-ones mask at the hot element). Four independent vi4 chains, ~3
//    ops per vec4 -- replaces the 128-fmaf dependent dot.
//  - row broadcast is ONE ballot + ONE shfl from the hit lane -- replaces
//    the 6-deep shfl_xor butterfly. nz |= t gives the hit mask exactly even
//    if the hot cossim value is +0.0.
//  - hinge accumulates into 4 independent vf4 chains.
// No LDS / no __syncthreads until the final block reduce; natural register
// allocation (round 4 proved forced min-waves causes scratch spill).
//
// Correct column contributes exactly MARGIN per row; subtracted once in the
// final reduce: loss = sum/N - MARGIN.
__global__ __launch_bounds__(BLOCK) void
mm_fused_kernel(const float* __restrict__ cossim,
                const int* __restrict__ target,
                float* __restrict__ partials) {
    const vf4* __restrict__ c4 = (const vf4*)cossim;
    const vi4* __restrict__ t4 = (const vi4*)target;
    const int lane = threadIdx.x & 63, wave = threadIdx.x >> 6;

    vf4 accv = {0.0f, 0.0f, 0.0f, 0.0f};
#pragma unroll
    for (int r = 0; r < ROWS_PER_WAVE; ++r) {
        const unsigned row = (blockIdx.x * WAVES + wave) * ROWS_PER_WAVE + r;
        const size_t rowv4 = (size_t)row * V4_PER_ROW + lane;

        // Issue target loads first (consumed first), then cossim: 32 x 16B
        // in flight per wave.
        vi4 t[16];
#pragma unroll
        for (int k = 0; k < 16; ++k)
            t[k] = t4[rowv4 + k * 64];
        vf4 c[16];
#pragma unroll
        for (int k = 0; k < 16; ++k)
            c[k] = c4[rowv4 + k * 64];

        // Integer one-hot extract + hit mask (independent chains).
        vi4 sv = {0, 0, 0, 0}, nz = {0, 0, 0, 0};
#pragma unroll
        for (int k = 0; k < 16; ++k) {
            const vi4 cb  = __builtin_bit_cast(vi4, c[k]);
            const vi4 msk = -t[k];          // 0 or all-ones per element
            sv |= cb & msk;
            nz |= t[k];
        }
        const int lanenz = (nz[0] | nz[1]) | (nz[2] | nz[3]);
        const unsigned long long m = __ballot(lanenz != 0);
        const int sb = (sv[0] | sv[1]) | (sv[2] | sv[3]);
        const float sval  = __builtin_bit_cast(float, sb);
        const float s_row = __shfl(sval, (int)__ffsll(m) - 1, 64);
        const float mc = MARGIN - s_row;

        // Hinge from held registers: 4 independent accumulator chains.
#pragma unroll
        for (int k = 0; k < 16; ++k) {
            accv[0] += fmaxf(mc + c[k][0], 0.0f);
            accv[1] += fmaxf(mc + c[k][1], 0.0f);
            accv[2] += fmaxf(mc + c[k][2], 0.0f);
            accv[3] += fmaxf(mc + c[k][3], 0.0f);
        }
    }

    float acc = (accv[0] + accv[1]) + (accv[2] + accv[3]);

    // Block-level reduction (only sync in the kernel).
#pragma unroll
    for (int off = 32; off > 0; off >>= 1)
        acc += __shfl_down(acc, off, 64);
    __shared__ float s_acc[WAVES];
    if (lane == 0) s_acc[wave] = acc;
    __syncthreads();
    if (threadIdx.x == 0)
        partials[blockIdx.x] = s_acc[0] + s_acc[1] + s_acc[2] + s_acc[3];
}

// Final reduce over NBLK partials. loss = sum/N - MARGIN.
__global__ __launch_bounds__(BLOCK) void
mm_reduce_kernel(const float* __restrict__ partials, float* __restrict__ out) {
    const int t = threadIdx.x;
    float acc = 0.0f;
    for (int i = t; i < NBLK; i += BLOCK) acc += partials[i];
#pragma unroll
    for (int off = 32; off > 0; off >>= 1)
        acc += __shfl_down(acc, off, 64);
    __shared__ float s_wave[BLOCK / 64];
    const int lane = t & 63, wave = t >> 6;
    if (lane == 0) s_wave[wave] = acc;
    __syncthreads();
    if (t == 0)
        out[0] = (s_wave[0] + s_wave[1] + s_wave[2] + s_wave[3]) * (1.0f / N_ROWS)
                 - MARGIN;
}

extern "C" void kernel_launch(void* const* d_in, const int* in_sizes, int n_in,
                              void* d_out, int out_size, void* d_ws, size_t ws_size,
                              hipStream_t stream) {
    const float* cossim = (const float*)d_in[0];
    const int*   target = (const int*)d_in[1];
    float* out      = (float*)d_out;
    float* partials = (float*)d_ws;                  // NBLK floats

    mm_fused_kernel<<<NBLK, BLOCK, 0, stream>>>(cossim, target, partials);
    mm_reduce_kernel<<<1, BLOCK, 0, stream>>>(partials, out);
}